// Round 8
// baseline (1408.379 us; speedup 1.0000x reference)
//
#include <hip/hip_runtime.h>
#include <math.h>

#define B_DIM 4
#define T_DIM 2048
#define D_DIM 1024
#define ETA 0.1f
#define N_ITERS 10

typedef unsigned short u16;
typedef __attribute__((ext_vector_type(8))) short bf8_t;   // 8 bf16 (4 VGPRs)
typedef __attribute__((ext_vector_type(4))) float f4_t;    // 4 fp32 acc
typedef __attribute__((ext_vector_type(16))) float f16v;   // 16 fp32 acc (32x32)

__device__ __forceinline__ u16 f2bf(float f) {
  union { float f; unsigned u; } x;
  x.f = f;
  unsigned r = x.u + 0x7FFFu + ((x.u >> 16) & 1u);  // RNE
  return (u16)(r >> 16);
}
__device__ __forceinline__ float bf2f(u16 h) {
  union { unsigned u; float f; } x;
  x.u = ((unsigned)h) << 16;
  return x.f;
}

__device__ __forceinline__ float soft_thresh(float v, float lam) {
  return copysignf(fmaxf(fabsf(v) - lam, 0.0f), v);
}

// ---------------------------------------------------------------------------
// bf16 MFMA NT GEMM core: C(128x128 at m0,n0) = A[M x K] * B^T (B is [N][K]).
// 256 threads = 4 waves (2x2), each wave 64x64 = 4x4 mfma 16x16x32 tiles.
// ---------------------------------------------------------------------------
__device__ __forceinline__ void mfma_gemm_nt(const u16* __restrict__ A,
                                             const u16* __restrict__ Bm,
                                             int lda, int ldb,
                                             int m0, int n0, int kEnd,
                                             f4_t acc[4][4]) {
  __shared__ short As[128][72];
  __shared__ short Bs[128][72];
  const int tid = threadIdx.x;
  const int lane = tid & 63;
  const int wave = tid >> 6;
  const int m16 = lane & 15;
  const int q = lane >> 4;
  const int wrow = (wave >> 1) * 64;
  const int wcol = (wave & 1) * 64;
  const int sr = tid >> 3;   // staging row base (0..31)
  const int sc8 = tid & 7;   // k-octet (8 bf16 = 16B)

  float4 apf[4], bpf[4];
#pragma unroll
  for (int p = 0; p < 4; ++p) {
    apf[p] = *(const float4*)(A + (size_t)(m0 + sr + p * 32) * lda + sc8 * 8);
    bpf[p] = *(const float4*)(Bm + (size_t)(n0 + sr + p * 32) * ldb + sc8 * 8);
  }

  for (int k0 = 0; k0 < kEnd; k0 += 64) {
    __syncthreads();
#pragma unroll
    for (int p = 0; p < 4; ++p) {
      *(float4*)&As[sr + p * 32][sc8 * 8] = apf[p];
      *(float4*)&Bs[sr + p * 32][sc8 * 8] = bpf[p];
    }
    __syncthreads();
    if (k0 + 64 < kEnd) {
      const int kn = k0 + 64 + sc8 * 8;
#pragma unroll
      for (int p = 0; p < 4; ++p) {
        apf[p] = *(const float4*)(A + (size_t)(m0 + sr + p * 32) * lda + kn);
        bpf[p] = *(const float4*)(Bm + (size_t)(n0 + sr + p * 32) * ldb + kn);
      }
    }
#pragma unroll
    for (int s = 0; s < 2; ++s) {
      bf8_t af[4], bb[4];
#pragma unroll
      for (int i = 0; i < 4; ++i)
        af[i] = *(const bf8_t*)&As[wrow + i * 16 + m16][s * 32 + q * 8];
#pragma unroll
      for (int j = 0; j < 4; ++j)
        bb[j] = *(const bf8_t*)&Bs[wcol + j * 16 + m16][s * 32 + q * 8];
#pragma unroll
      for (int i = 0; i < 4; ++i)
#pragma unroll
        for (int j = 0; j < 4; ++j)
          acc[i][j] = __builtin_amdgcn_mfma_f32_16x16x32_bf16(
              af[i], bb[j], acc[i][j], 0, 0, 0);
    }
    __syncthreads();
  }
}

// C/D layout 16x16 (verified m89): col = lane&15, row = (lane>>4)*4 + reg.
#define EPI_PREAMBLE                                   \
  const int tid = threadIdx.x;                         \
  const int lane = tid & 63;                           \
  const int wave = tid >> 6;                           \
  const int m16 = lane & 15;                           \
  const int q = lane >> 4;                             \
  const int wrow = (wave >> 1) * 64;                   \
  const int wcol = (wave & 1) * 64;

// ---------------------------------------------------------------------------
__global__ __launch_bounds__(256) void cvt_bf16_kernel(
    const float* __restrict__ src, u16* __restrict__ dst, int n4) {
  const int i = blockIdx.x * 256 + threadIdx.x;
  if (i >= n4) return;
  const float4 v = ((const float4*)src)[i];
  ushort4 o;
  o.x = f2bf(v.x); o.y = f2bf(v.y); o.z = f2bf(v.z); o.w = f2bf(v.w);
  ((ushort4*)dst)[i] = o;
}

// ---------------------------------------------------------------------------
// G -> fragment-sequential swizzled layout for mfma_32x32x16 B-operand:
// Gsw[t][c][lane][8] with n = t*32 + (lane&31), k = c*16 + (lane>>5)*8 + j.
// Each (wave,tile,k-step) fragment load becomes base + lane*16B: coalesced.
// G = 0.5*(Graw+Graw^T), zero diag, bf16.
// ---------------------------------------------------------------------------
__global__ __launch_bounds__(256) void prep_Gsw_kernel(
    const float* __restrict__ Graw, u16* __restrict__ Gsw) {
  const int idx = blockIdx.x * 256 + threadIdx.x;  // 0 .. 32*64*64-1
  const int lane = idx & 63;
  const int c = (idx >> 6) & 63;
  const int t = idx >> 12;
  const int n = t * 32 + (lane & 31);
  const int k0 = c * 16 + (lane >> 5) * 8;
  union { u16 s[8]; float4 v; } o;
#pragma unroll
  for (int j = 0; j < 8; ++j) {
    const int k = k0 + j;
    const float g = (n == k)
        ? 0.0f
        : 0.5f * (Graw[(size_t)n * D_DIM + k] + Graw[(size_t)k * D_DIM + n]);
    o.s[j] = f2bf(g);
  }
  *(float4*)(Gsw + (size_t)idx * 8) = o.v;
}

// ---------------------------------------------------------------------------
// qkv = x @ Wqkv^T -> all outputs bf16: uqb / ukb (in d_out) / vbf.
// XCD-confined mapping: XCD x (= bid%8, round-robin dispatch) owns n-blocks
// {3x, 3x+1, 3x+2} for ALL m -> per-XCD W slice = 384 cols x 1024 = 768 KB
// (L2-resident), x m-panels reused 3x consecutively. Kills W thrash.
// ---------------------------------------------------------------------------
__global__ __launch_bounds__(256) void qkv_mfma_kernel(
    const u16* __restrict__ xbf, const u16* __restrict__ Wbf,
    u16* __restrict__ uqb, u16* __restrict__ ukb, u16* __restrict__ vbf) {
  const int bid = blockIdx.x;
  const int xcd = bid & 7;
  const int idx = bid >> 3;        // 0..191
  const int nl = idx % 3;
  const int m0 = (idx / 3) * 128;  // 0..63 * 128
  const int n0 = (xcd * 3 + nl) * 128;
  f4_t acc[4][4];
#pragma unroll
  for (int i = 0; i < 4; ++i)
#pragma unroll
    for (int j = 0; j < 4; ++j) acc[i][j] = (f4_t){0.f, 0.f, 0.f, 0.f};
  mfma_gemm_nt(xbf, Wbf, D_DIM, D_DIM, m0, n0, D_DIM, acc);
  EPI_PREAMBLE
  const int which = n0 >> 10;
  u16* dst = (which == 0) ? uqb : ((which == 1) ? ukb : vbf);
  const int nloc0 = n0 & 1023;
#pragma unroll
  for (int i = 0; i < 4; ++i)
#pragma unroll
    for (int j = 0; j < 4; ++j) {
      const int cc = nloc0 + wcol + j * 16 + m16;
#pragma unroll
      for (int r2 = 0; r2 < 4; ++r2) {
        const size_t rr = m0 + wrow + i * 16 + q * 4 + r2;
        dst[rr * D_DIM + cc] = f2bf(acc[i][j][r2]);
      }
    }
}

// ---------------------------------------------------------------------------
__global__ __launch_bounds__(256) void transpose_bf16_kernel(
    const u16* __restrict__ src, u16* __restrict__ dst) {
  __shared__ short Ls[64][72];
  const int b = blockIdx.z;
  const int d0 = blockIdx.x * 64;
  const int t0 = blockIdx.y * 64;
  const int tid = threadIdx.x;
#pragma unroll
  for (int rep = 0; rep < 2; ++rep) {
    const int u = rep * 256 + tid;
    const int r = u >> 3;
    const int c8 = u & 7;
    const float4 v = *(const float4*)(src + (size_t)b * T_DIM * D_DIM +
                                      (size_t)(t0 + r) * D_DIM + d0 + c8 * 8);
    *(float4*)&Ls[r][c8 * 8] = v;
  }
  __syncthreads();
#pragma unroll
  for (int rep = 0; rep < 2; ++rep) {
    const int u = rep * 256 + tid;
    const int d = u >> 3;
    const int t8 = u & 7;
    union { u16 s[8]; float4 v; } tmp;
#pragma unroll
    for (int l = 0; l < 8; ++l) tmp.s[l] = (u16)Ls[t8 * 8 + l][d];
    *(float4*)(dst + (size_t)b * D_DIM * T_DIM + (size_t)(d0 + d) * T_DIM +
               t0 + t8 * 8) = tmp.v;
  }
}

// ---------------------------------------------------------------------------
// Fused LCA chain v5: same structure as R7 (proven: no spill, 0 conflicts),
// with the G-fragment prefetch pipeline deepened to 4 slots (distance 3
// c-steps ~ 100-150 cyc, covering most of the ~200 cyc L2 latency).
// bb regs: 4 slots x 4 tiles x 4 VGPR = 64 -> ~220 unified total, still
// <= 256 => occupancy unchanged (2 waves/SIMD).
// ---------------------------------------------------------------------------
__global__ __launch_bounds__(512) void lca_fused_kernel(
    const u16* __restrict__ uqb, const u16* __restrict__ ukb,
    const u16* __restrict__ Gqsw, const u16* __restrict__ Gksw,
    const float* __restrict__ llq, const float* __restrict__ llk,
    u16* __restrict__ aq_out, u16* __restrict__ ak_out) {
  __shared__ u16 a_lds[32][1032];
  const int b = blockIdx.x;
  const int chain = (b >> 2) & 1;                 // b%8: 0-3 q, 4-7 k (XCD map)
  const int mb = ((b >> 3) << 2) | (b & 3);       // 0..255
  const int m0 = mb * 32;
  const u16* __restrict__ ub = chain ? ukb : uqb;
  const u16* __restrict__ Gsw = chain ? Gksw : Gqsw;
  u16* __restrict__ aout = chain ? ak_out : aq_out;
  const float lam = expf(chain ? llk[0] : llq[0]);

  const int tid = threadIdx.x;
  const int lane = tid & 63;
  const int wave = tid >> 6;      // 0..7
  const int n32 = lane & 31;
  const int l5 = lane >> 5;       // 0/1
  const int col0 = wave * 128;

  float vreg[4][16];

  // ---- init (iter 0): v = ETA*u ; a0 = soft(v) into a_lds
#pragma unroll
  for (int nt = 0; nt < 4; ++nt) {
    const int col_g = col0 + nt * 32 + n32;
#pragma unroll
    for (int reg = 0; reg < 16; ++reg) {
      const int row = (reg & 3) + 8 * (reg >> 2) + 4 * l5;
      const float uu = bf2f(ub[(size_t)(m0 + row) * D_DIM + col_g]);
      const float v = ETA * uu;
      vreg[nt][reg] = v;
      a_lds[row][col_g] = f2bf(soft_thresh(v, lam));
    }
  }

  // per-tile fragment base: Gsw + t*64*512 + lane*8 (elems); step c = +512
  const u16* gb[4];
#pragma unroll
  for (int nt = 0; nt < 4; ++nt)
    gb[nt] = Gsw + ((size_t)(wave * 4 + nt) * 64) * 512 + lane * 8;

  for (int it = 1; it < N_ITERS; ++it) {
    __syncthreads();  // a_lds complete (init or previous epilogue)
    f16v acc[4];
#pragma unroll
    for (int nt = 0; nt < 4; ++nt)
#pragma unroll
      for (int r = 0; r < 16; ++r) acc[nt][r] = 0.0f;

    // 4-slot rotating prefetch: slots hold c, c+1, c+2, c+3
    bf8_t bb[4][4];
#pragma unroll
    for (int s = 0; s < 3; ++s)
#pragma unroll
      for (int nt = 0; nt < 4; ++nt)
        bb[s][nt] = *(const bf8_t*)(gb[nt] + (size_t)s * 512);

#pragma unroll 1
    for (int c = 0; c < 64; c += 4) {
#pragma unroll
      for (int j = 0; j < 4; ++j) {
        const int s = c + j;          // current k-step
        const int nx = s + 3;         // prefetch target
        if (nx < 64) {
#pragma unroll
          for (int nt = 0; nt < 4; ++nt)
            bb[nx & 3][nt] = *(const bf8_t*)(gb[nt] + (size_t)nx * 512);
        }
        const bf8_t af = *(const bf8_t*)&a_lds[n32][s * 16 + l5 * 8];
#pragma unroll
        for (int nt = 0; nt < 4; ++nt)
          acc[nt] = __builtin_amdgcn_mfma_f32_32x32x16_bf16(af, bb[s & 3][nt],
                                                            acc[nt], 0, 0, 0);
      }
    }
    __syncthreads();  // all waves done READING a_lds; safe to overwrite

    const bool last = (it == N_ITERS - 1);
#pragma unroll
    for (int nt = 0; nt < 4; ++nt) {
      const int col_g = col0 + nt * 32 + n32;
#pragma unroll
      for (int reg = 0; reg < 16; ++reg) {
        const int row = (reg & 3) + 8 * (reg >> 2) + 4 * l5;
        const float uu = bf2f(ub[(size_t)(m0 + row) * D_DIM + col_g]);
        float v = vreg[nt][reg];
        v += ETA * (uu - v - acc[nt][reg]);
        vreg[nt][reg] = v;
        const u16 av = f2bf(soft_thresh(v, lam));
        a_lds[row][col_g] = av;
        if (last) aout[(size_t)(m0 + row) * D_DIM + col_g] = av;
      }
    }
  }
}

// ---------------------------------------------------------------------------
__global__ __launch_bounds__(256) void scores_mfma_kernel(
    const u16* __restrict__ aq, const u16* __restrict__ ak,
    float* __restrict__ sc) {
  const int b = blockIdx.z;
  const int m0 = blockIdx.y * 128;
  const int n0 = blockIdx.x * 128;
  if (n0 > m0 + 127) return;  // uniform early exit, before any barrier
  f4_t acc[4][4];
#pragma unroll
  for (int i = 0; i < 4; ++i)
#pragma unroll
    for (int j = 0; j < 4; ++j) acc[i][j] = (f4_t){0.f, 0.f, 0.f, 0.f};
  mfma_gemm_nt(aq + (size_t)b * T_DIM * D_DIM,
               ak + (size_t)b * T_DIM * D_DIM, D_DIM, D_DIM, m0, n0, D_DIM,
               acc);
  EPI_PREAMBLE
  float* out = sc + (size_t)b * T_DIM * T_DIM;
  const float scale = 0.03125f;  // 1/sqrt(1024)
#pragma unroll
  for (int i = 0; i < 4; ++i)
#pragma unroll
    for (int j = 0; j < 4; ++j) {
      const int cc = n0 + wcol + j * 16 + m16;
#pragma unroll
      for (int r = 0; r < 4; ++r) {
        const size_t rr = m0 + wrow + i * 16 + q * 4 + r;
        out[rr * T_DIM + cc] = acc[i][j][r] * scale;
      }
    }
}

// ---------------------------------------------------------------------------
// Causal softmax, one WAVE per row (no LDS, no barriers): 4 rows / block.
// ---------------------------------------------------------------------------
__global__ __launch_bounds__(256) void softmax_attn_kernel(
    const float* __restrict__ sc, u16* __restrict__ attn) {
  const int r = blockIdx.x * 4 + (threadIdx.x >> 6);  // global row 0..8191
  const int lane = threadIdx.x & 63;
  const int b = r >> 11;
  const int i = r & (T_DIM - 1);
  const float* row = sc + ((size_t)b * T_DIM + i) * T_DIM;
  u16* arow = attn + ((size_t)b * T_DIM + i) * T_DIM;
  const int len = i + 1;

  float mx = -INFINITY;
  for (int j = lane; j < len; j += 64) mx = fmaxf(mx, row[j]);
#pragma unroll
  for (int off = 32; off > 0; off >>= 1)
    mx = fmaxf(mx, __shfl_xor(mx, off));

  float sum = 0.0f;
  for (int j = lane; j < len; j += 64) sum += __expf(row[j] - mx);
#pragma unroll
  for (int off = 32; off > 0; off >>= 1) sum += __shfl_xor(sum, off);
  const float inv = 1.0f / sum;

  for (int j = lane; j < len; j += 64)
    arow[j] = f2bf(__expf(row[j] - mx) * inv);
  for (int j = len + ((64 - (len & 63)) & 63) + lane - 64 + 64; false;) {}
  for (int j = len + lane; j < T_DIM; j += 64) arow[j] = 0;
}

// ---------------------------------------------------------------------------
__global__ __launch_bounds__(256) void attnv_mfma_kernel(
    const u16* __restrict__ attn, const u16* __restrict__ vT,
    u16* __restrict__ o1) {
  const int b = blockIdx.z;
  const int m0 = blockIdx.y * 128;
  const int n0 = blockIdx.x * 128;
  f4_t acc[4][4];
#pragma unroll
  for (int i = 0; i < 4; ++i)
#pragma unroll
    for (int j = 0; j < 4; ++j) acc[i][j] = (f4_t){0.f, 0.f, 0.f, 0.f};
  mfma_gemm_nt(attn + (size_t)b * T_DIM * T_DIM,
               vT + (size_t)b * D_DIM * T_DIM, T_DIM, T_DIM, m0, n0,
               m0 + 128, acc);
  EPI_PREAMBLE
  u16* out = o1 + (size_t)b * T_DIM * D_DIM;
#pragma unroll
  for (int i = 0; i < 4; ++i)
#pragma unroll
    for (int j = 0; j < 4; ++j) {
      const int cc = n0 + wcol + j * 16 + m16;
#pragma unroll
      for (int r = 0; r < 4; ++r) {
        const size_t rr = m0 + wrow + i * 16 + q * 4 + r;
        out[rr * D_DIM + cc] = f2bf(acc[i][j][r]);
      }
    }
}

// ---------------------------------------------------------------------------
__global__ __launch_bounds__(256) void out_mfma_kernel(
    const u16* __restrict__ o1, const u16* __restrict__ Wbf,
    float* __restrict__ out) {
  f4_t acc[4][4];
#pragma unroll
  for (int i = 0; i < 4; ++i)
#pragma unroll
    for (int j = 0; j < 4; ++j) acc[i][j] = (f4_t){0.f, 0.f, 0.f, 0.f};
  const int m0 = blockIdx.y * 128;
  const int n0 = blockIdx.x * 128;
  mfma_gemm_nt(o1, Wbf, D_DIM, D_DIM, m0, n0, D_DIM, acc);
  EPI_PREAMBLE
#pragma unroll
  for (int i = 0; i < 4; ++i)
#pragma unroll
    for (int j = 0; j < 4; ++j) {
      const int cc = n0 + wcol + j * 16 + m16;
#pragma unroll
      for (int r = 0; r < 4; ++r) {
        const size_t rr = m0 + wrow + i * 16 + q * 4 + r;
        out[rr * D_DIM + cc] = acc[i][j][r];
      }
    }
}

// ---------------------------------------------------------------------------
// Workspace (SZ = B*T*D = 8,388,608), total ~156 MiB (same as proven):
//   R0: 2*SZ fp32 (64 MiB) = scores; hosts xbf (bf16 x) early (dead by then)
//   uqb, vbf, vT, bq1(aq), bkf(ak): 5 x SZ u16 (80 MiB)
//   wqkvb 3M, woutb 1M, gqsw 1M, gksw 1M u16 (12 MiB)
// ukb (bf16 u_k) lives in d_out, fully overwritten by the final GEMM.
// attn (2*SZ u16) over [bq1|bkf] (dead after scores); o1 over uqb (dead).
// ---------------------------------------------------------------------------
extern "C" void kernel_launch(void* const* d_in, const int* in_sizes, int n_in,
                              void* d_out, int out_size, void* d_ws,
                              size_t ws_size, hipStream_t stream) {
  (void)in_sizes; (void)n_in; (void)out_size; (void)ws_size;
  const float* x = (const float*)d_in[0];
  const float* Wqkv = (const float*)d_in[1];
  const float* Wout = (const float*)d_in[2];
  const float* Gq_raw = (const float*)d_in[3];
  const float* llq = (const float*)d_in[4];
  const float* Gk_raw = (const float*)d_in[5];
  const float* llk = (const float*)d_in[6];
  float* out = (float*)d_out;

  const size_t SZ = (size_t)B_DIM * T_DIM * D_DIM;  // 8,388,608
  u16* base = (u16*)d_ws;
  float* sc = (float*)base;          // 2*SZ fp32 (= 4*SZ u16)
  u16* xbf = base;                   // bf16 x over R0 start (dead before sc)
  u16* uqb = base + 4 * SZ;
  u16* vbf = base + 5 * SZ;
  u16* vT  = base + 6 * SZ;
  u16* bq1 = base + 7 * SZ;          // final aq
  u16* bkf = base + 8 * SZ;          // final ak
  u16* wqkvb = base + 9 * SZ;                    // 3M
  u16* woutb = wqkvb + 3 * 1024 * 1024;          // 1M
  u16* gqsw = woutb + 1024 * 1024;               // 1M
  u16* gksw = gqsw + 1024 * 1024;                // 1M
  u16* ukb = (u16*)d_out;            // bf16 u_k in d_out until final GEMM
  u16* attn = bq1;                   // 2*SZ over bq1+bkf (dead after scores)
  u16* o1 = uqb;                     // dead after LCA

  const dim3 blk(256);

  cvt_bf16_kernel<<<dim3((int)(SZ / 4 / 256)), blk, 0, stream>>>(x, xbf,
                                                                 (int)(SZ / 4));
  cvt_bf16_kernel<<<dim3(3 * 1024), blk, 0, stream>>>(Wqkv, wqkvb,
                                                      3 * 1024 * 1024 / 4);
  cvt_bf16_kernel<<<dim3(1024), blk, 0, stream>>>(Wout, woutb,
                                                  1024 * 1024 / 4);
  prep_Gsw_kernel<<<dim3(512), blk, 0, stream>>>(Gq_raw, gqsw);
  prep_Gsw_kernel<<<dim3(512), blk, 0, stream>>>(Gk_raw, gksw);

  // qkv: 1536 blocks, XCD-confined n-slices
  qkv_mfma_kernel<<<dim3(1536), blk, 0, stream>>>(xbf, wqkvb, uqb, ukb, vbf);
  transpose_bf16_kernel<<<dim3(16, 32, 4), blk, 0, stream>>>(vbf, vT);

  // fused LCA v5: both chains, one dispatch, 512-thread blocks
  lca_fused_kernel<<<dim3(512), dim3(512), 0, stream>>>(uqb, ukb, gqsw, gksw,
                                                        llq, llk, bq1, bkf);

  scores_mfma_kernel<<<dim3(16, 16, 4), blk, 0, stream>>>(bq1, bkf, sc);
  softmax_attn_kernel<<<dim3(B_DIM * T_DIM / 4), blk, 0, stream>>>(sc, attn);
  attnv_mfma_kernel<<<dim3(8, 16, 4), blk, 0, stream>>>(attn, vT, o1);
  out_mfma_kernel<<<dim3(8, 64), blk, 0, stream>>>(o1, woutb, out);
}

// Round 9
// 1219.079 us; speedup vs baseline: 1.1553x; 1.1553x over previous
//
#include <hip/hip_runtime.h>
#include <math.h>

#define B_DIM 4
#define T_DIM 2048
#define D_DIM 1024
#define ETA 0.1f
#define N_ITERS 10

typedef unsigned short u16;
typedef __attribute__((ext_vector_type(8))) short bf8_t;   // 8 bf16 (4 VGPRs)
typedef __attribute__((ext_vector_type(4))) float f4_t;    // 4 fp32 acc
typedef __attribute__((ext_vector_type(16))) float f16v;   // 16 fp32 acc (32x32)

__device__ __forceinline__ u16 f2bf(float f) {
  union { float f; unsigned u; } x;
  x.f = f;
  unsigned r = x.u + 0x7FFFu + ((x.u >> 16) & 1u);  // RNE
  return (u16)(r >> 16);
}
__device__ __forceinline__ float bf2f(u16 h) {
  union { unsigned u; float f; } x;
  x.u = ((unsigned)h) << 16;
  return x.f;
}

__device__ __forceinline__ float soft_thresh(float v, float lam) {
  return copysignf(fmaxf(fabsf(v) - lam, 0.0f), v);
}

// ---------------------------------------------------------------------------
// bf16 MFMA NT GEMM core: C(128x128 at m0,n0) = A[M x K] * B^T (B is [N][K]).
// 256 threads = 4 waves (2x2), each wave 64x64 = 4x4 mfma 16x16x32 tiles.
// 2 barriers per K-step (trailing sync removed: the leading sync of step i+1
// already orders compute(i) vs LDS-write(i+1)).
// ---------------------------------------------------------------------------
__device__ __forceinline__ void mfma_gemm_nt(const u16* __restrict__ A,
                                             const u16* __restrict__ Bm,
                                             int lda, int ldb,
                                             int m0, int n0, int kEnd,
                                             f4_t acc[4][4]) {
  __shared__ short As[128][72];
  __shared__ short Bs[128][72];
  const int tid = threadIdx.x;
  const int lane = tid & 63;
  const int wave = tid >> 6;
  const int m16 = lane & 15;
  const int q = lane >> 4;
  const int wrow = (wave >> 1) * 64;
  const int wcol = (wave & 1) * 64;
  const int sr = tid >> 3;   // staging row base (0..31)
  const int sc8 = tid & 7;   // k-octet (8 bf16 = 16B)

  float4 apf[4], bpf[4];
#pragma unroll
  for (int p = 0; p < 4; ++p) {
    apf[p] = *(const float4*)(A + (size_t)(m0 + sr + p * 32) * lda + sc8 * 8);
    bpf[p] = *(const float4*)(Bm + (size_t)(n0 + sr + p * 32) * ldb + sc8 * 8);
  }

  for (int k0 = 0; k0 < kEnd; k0 += 64) {
    __syncthreads();
#pragma unroll
    for (int p = 0; p < 4; ++p) {
      *(float4*)&As[sr + p * 32][sc8 * 8] = apf[p];
      *(float4*)&Bs[sr + p * 32][sc8 * 8] = bpf[p];
    }
    __syncthreads();
    if (k0 + 64 < kEnd) {
      const int kn = k0 + 64 + sc8 * 8;
#pragma unroll
      for (int p = 0; p < 4; ++p) {
        apf[p] = *(const float4*)(A + (size_t)(m0 + sr + p * 32) * lda + kn);
        bpf[p] = *(const float4*)(Bm + (size_t)(n0 + sr + p * 32) * ldb + kn);
      }
    }
#pragma unroll
    for (int s = 0; s < 2; ++s) {
      bf8_t af[4], bb[4];
#pragma unroll
      for (int i = 0; i < 4; ++i)
        af[i] = *(const bf8_t*)&As[wrow + i * 16 + m16][s * 32 + q * 8];
#pragma unroll
      for (int j = 0; j < 4; ++j)
        bb[j] = *(const bf8_t*)&Bs[wcol + j * 16 + m16][s * 32 + q * 8];
#pragma unroll
      for (int i = 0; i < 4; ++i)
#pragma unroll
        for (int j = 0; j < 4; ++j)
          acc[i][j] = __builtin_amdgcn_mfma_f32_16x16x32_bf16(
              af[i], bb[j], acc[i][j], 0, 0, 0);
    }
  }
}

// C/D layout 16x16 (verified m89): col = lane&15, row = (lane>>4)*4 + reg.
#define EPI_PREAMBLE                                   \
  const int tid = threadIdx.x;                         \
  const int lane = tid & 63;                           \
  const int wave = tid >> 6;                           \
  const int m16 = lane & 15;                           \
  const int q = lane >> 4;                             \
  const int wrow = (wave >> 1) * 64;                   \
  const int wcol = (wave & 1) * 64;

// ---------------------------------------------------------------------------
__global__ __launch_bounds__(256) void cvt_bf16_kernel(
    const float* __restrict__ src, u16* __restrict__ dst, int n4) {
  const int i = blockIdx.x * 256 + threadIdx.x;
  if (i >= n4) return;
  const float4 v = ((const float4*)src)[i];
  ushort4 o;
  o.x = f2bf(v.x); o.y = f2bf(v.y); o.z = f2bf(v.z); o.w = f2bf(v.w);
  ((ushort4*)dst)[i] = o;
}

// ---------------------------------------------------------------------------
// G -> fragment-sequential swizzled layout for mfma_32x32x16 B-operand:
// Gsw[t][c][lane][8] with n = t*32 + (lane&31), k = c*16 + (lane>>5)*8 + j.
// Each (wave,tile,k-step) fragment load becomes base + lane*16B: coalesced.
// G = 0.5*(Graw+Graw^T), zero diag, bf16.
// ---------------------------------------------------------------------------
__global__ __launch_bounds__(256) void prep_Gsw_kernel(
    const float* __restrict__ Graw, u16* __restrict__ Gsw) {
  const int idx = blockIdx.x * 256 + threadIdx.x;  // 0 .. 32*64*64-1
  const int lane = idx & 63;
  const int c = (idx >> 6) & 63;
  const int t = idx >> 12;
  const int n = t * 32 + (lane & 31);
  const int k0 = c * 16 + (lane >> 5) * 8;
  union { u16 s[8]; float4 v; } o;
#pragma unroll
  for (int j = 0; j < 8; ++j) {
    const int k = k0 + j;
    const float g = (n == k)
        ? 0.0f
        : 0.5f * (Graw[(size_t)n * D_DIM + k] + Graw[(size_t)k * D_DIM + n]);
    o.s[j] = f2bf(g);
  }
  *(float4*)(Gsw + (size_t)idx * 8) = o.v;
}

// ---------------------------------------------------------------------------
// qkv = x @ Wqkv^T -> all outputs bf16: uqb / ukb (in d_out) / vbf.
// 1-D grid of 1536 blocks, supertile-swizzled (R7-proven).
// ---------------------------------------------------------------------------
__global__ __launch_bounds__(256) void qkv_mfma_kernel(
    const u16* __restrict__ xbf, const u16* __restrict__ Wbf,
    u16* __restrict__ uqb, u16* __restrict__ ukb, u16* __restrict__ vbf) {
  const int bid = blockIdx.x;
  const int g = bid / 192;
  const int r = bid % 192;
  const int m0 = (g * 8 + (r & 7)) * 128;
  const int n0 = (r >> 3) * 128;
  f4_t acc[4][4];
#pragma unroll
  for (int i = 0; i < 4; ++i)
#pragma unroll
    for (int j = 0; j < 4; ++j) acc[i][j] = (f4_t){0.f, 0.f, 0.f, 0.f};
  mfma_gemm_nt(xbf, Wbf, D_DIM, D_DIM, m0, n0, D_DIM, acc);
  EPI_PREAMBLE
  const int which = n0 >> 10;
  u16* dst = (which == 0) ? uqb : ((which == 1) ? ukb : vbf);
  const int nloc0 = n0 & 1023;
#pragma unroll
  for (int i = 0; i < 4; ++i)
#pragma unroll
    for (int j = 0; j < 4; ++j) {
      const int cc = nloc0 + wcol + j * 16 + m16;
#pragma unroll
      for (int r2 = 0; r2 < 4; ++r2) {
        const size_t rr = m0 + wrow + i * 16 + q * 4 + r2;
        dst[rr * D_DIM + cc] = f2bf(acc[i][j][r2]);
      }
    }
}

// ---------------------------------------------------------------------------
__global__ __launch_bounds__(256) void transpose_bf16_kernel(
    const u16* __restrict__ src, u16* __restrict__ dst) {
  __shared__ short Ls[64][72];
  const int b = blockIdx.z;
  const int d0 = blockIdx.x * 64;
  const int t0 = blockIdx.y * 64;
  const int tid = threadIdx.x;
#pragma unroll
  for (int rep = 0; rep < 2; ++rep) {
    const int u = rep * 256 + tid;
    const int r = u >> 3;
    const int c8 = u & 7;
    const float4 v = *(const float4*)(src + (size_t)b * T_DIM * D_DIM +
                                      (size_t)(t0 + r) * D_DIM + d0 + c8 * 8);
    *(float4*)&Ls[r][c8 * 8] = v;
  }
  __syncthreads();
#pragma unroll
  for (int rep = 0; rep < 2; ++rep) {
    const int u = rep * 256 + tid;
    const int d = u >> 3;
    const int t8 = u & 7;
    union { u16 s[8]; float4 v; } tmp;
#pragma unroll
    for (int l = 0; l < 8; ++l) tmp.s[l] = (u16)Ls[t8 * 8 + l][d];
    *(float4*)(dst + (size_t)b * D_DIM * T_DIM + (size_t)(d0 + d) * T_DIM +
               t0 + t8 * 8) = tmp.v;
  }
}

// ---------------------------------------------------------------------------
// Fused LCA chain (R7-proven exact): all 10 iterations in one kernel,
// mfma_32x32x16, 2-slot G-fragment register prefetch. Register budget
// vreg 64 + bb 32 + misc fits the 128-arch-VGPR allocation: no spill
// (R8's 4-slot variant spilled -> reverted).
// ---------------------------------------------------------------------------
__global__ __launch_bounds__(512) void lca_fused_kernel(
    const u16* __restrict__ uqb, const u16* __restrict__ ukb,
    const u16* __restrict__ Gqsw, const u16* __restrict__ Gksw,
    const float* __restrict__ llq, const float* __restrict__ llk,
    u16* __restrict__ aq_out, u16* __restrict__ ak_out) {
  __shared__ u16 a_lds[32][1032];
  const int b = blockIdx.x;
  const int chain = (b >> 2) & 1;                 // b%8: 0-3 q, 4-7 k (XCD map)
  const int mb = ((b >> 3) << 2) | (b & 3);       // 0..255
  const int m0 = mb * 32;
  const u16* __restrict__ ub = chain ? ukb : uqb;
  const u16* __restrict__ Gsw = chain ? Gksw : Gqsw;
  u16* __restrict__ aout = chain ? ak_out : aq_out;
  const float lam = expf(chain ? llk[0] : llq[0]);

  const int tid = threadIdx.x;
  const int lane = tid & 63;
  const int wave = tid >> 6;      // 0..7
  const int n32 = lane & 31;
  const int l5 = lane >> 5;       // 0/1
  const int col0 = wave * 128;

  float vreg[4][16];

  // ---- init (iter 0): v = ETA*u ; a0 = soft(v) into a_lds
#pragma unroll
  for (int nt = 0; nt < 4; ++nt) {
    const int col_g = col0 + nt * 32 + n32;
#pragma unroll
    for (int reg = 0; reg < 16; ++reg) {
      const int row = (reg & 3) + 8 * (reg >> 2) + 4 * l5;
      const float uu = bf2f(ub[(size_t)(m0 + row) * D_DIM + col_g]);
      const float v = ETA * uu;
      vreg[nt][reg] = v;
      a_lds[row][col_g] = f2bf(soft_thresh(v, lam));
    }
  }

  // per-tile fragment base: Gsw + t*64*512 + lane*8 (elems); step c = +512
  const u16* gb[4];
#pragma unroll
  for (int nt = 0; nt < 4; ++nt)
    gb[nt] = Gsw + ((size_t)(wave * 4 + nt) * 64) * 512 + lane * 8;

  for (int it = 1; it < N_ITERS; ++it) {
    __syncthreads();  // a_lds complete (init or previous epilogue)
    f16v acc[4];
#pragma unroll
    for (int nt = 0; nt < 4; ++nt)
#pragma unroll
      for (int r = 0; r < 16; ++r) acc[nt][r] = 0.0f;

    bf8_t bb0[4], bb1[4];
#pragma unroll
    for (int nt = 0; nt < 4; ++nt) bb0[nt] = *(const bf8_t*)(gb[nt]);

#pragma unroll 1
    for (int c = 0; c < 64; c += 2) {
#pragma unroll
      for (int nt = 0; nt < 4; ++nt)
        bb1[nt] = *(const bf8_t*)(gb[nt] + (size_t)(c + 1) * 512);
      {
        const bf8_t af = *(const bf8_t*)&a_lds[n32][c * 16 + l5 * 8];
#pragma unroll
        for (int nt = 0; nt < 4; ++nt)
          acc[nt] = __builtin_amdgcn_mfma_f32_32x32x16_bf16(af, bb0[nt],
                                                            acc[nt], 0, 0, 0);
      }
      if (c + 2 < 64) {
#pragma unroll
        for (int nt = 0; nt < 4; ++nt)
          bb0[nt] = *(const bf8_t*)(gb[nt] + (size_t)(c + 2) * 512);
      }
      {
        const bf8_t af = *(const bf8_t*)&a_lds[n32][(c + 1) * 16 + l5 * 8];
#pragma unroll
        for (int nt = 0; nt < 4; ++nt)
          acc[nt] = __builtin_amdgcn_mfma_f32_32x32x16_bf16(af, bb1[nt],
                                                            acc[nt], 0, 0, 0);
      }
    }
    __syncthreads();  // all waves done READING a_lds; safe to overwrite

    const bool last = (it == N_ITERS - 1);
#pragma unroll
    for (int nt = 0; nt < 4; ++nt) {
      const int col_g = col0 + nt * 32 + n32;
#pragma unroll
      for (int reg = 0; reg < 16; ++reg) {
        const int row = (reg & 3) + 8 * (reg >> 2) + 4 * l5;
        const float uu = bf2f(ub[(size_t)(m0 + row) * D_DIM + col_g]);
        float v = vreg[nt][reg];
        v += ETA * (uu - v - acc[nt][reg]);
        vreg[nt][reg] = v;
        const u16 av = f2bf(soft_thresh(v, lam));
        a_lds[row][col_g] = av;
        if (last) aout[(size_t)(m0 + row) * D_DIM + col_g] = av;
      }
    }
  }
}

// ---------------------------------------------------------------------------
__global__ __launch_bounds__(256) void scores_mfma_kernel(
    const u16* __restrict__ aq, const u16* __restrict__ ak,
    float* __restrict__ sc) {
  const int b = blockIdx.z;
  const int m0 = blockIdx.y * 128;
  const int n0 = blockIdx.x * 128;
  if (n0 > m0 + 127) return;  // uniform early exit, before any barrier
  f4_t acc[4][4];
#pragma unroll
  for (int i = 0; i < 4; ++i)
#pragma unroll
    for (int j = 0; j < 4; ++j) acc[i][j] = (f4_t){0.f, 0.f, 0.f, 0.f};
  mfma_gemm_nt(aq + (size_t)b * T_DIM * D_DIM,
               ak + (size_t)b * T_DIM * D_DIM, D_DIM, D_DIM, m0, n0, D_DIM,
               acc);
  EPI_PREAMBLE
  float* out = sc + (size_t)b * T_DIM * T_DIM;
  const float scale = 0.03125f;  // 1/sqrt(1024)
#pragma unroll
  for (int i = 0; i < 4; ++i)
#pragma unroll
    for (int j = 0; j < 4; ++j) {
      const int cc = n0 + wcol + j * 16 + m16;
#pragma unroll
      for (int r = 0; r < 4; ++r) {
        const size_t rr = m0 + wrow + i * 16 + q * 4 + r;
        out[rr * T_DIM + cc] = acc[i][j][r] * scale;
      }
    }
}

// ---------------------------------------------------------------------------
// Causal softmax, one WAVE per row (no LDS, no barriers): 4 rows / block.
// ---------------------------------------------------------------------------
__global__ __launch_bounds__(256) void softmax_attn_kernel(
    const float* __restrict__ sc, u16* __restrict__ attn) {
  const int r = blockIdx.x * 4 + (threadIdx.x >> 6);  // global row 0..8191
  const int lane = threadIdx.x & 63;
  const int b = r >> 11;
  const int i = r & (T_DIM - 1);
  const float* row = sc + ((size_t)b * T_DIM + i) * T_DIM;
  u16* arow = attn + ((size_t)b * T_DIM + i) * T_DIM;
  const int len = i + 1;

  float mx = -INFINITY;
  for (int j = lane; j < len; j += 64) mx = fmaxf(mx, row[j]);
#pragma unroll
  for (int off = 32; off > 0; off >>= 1)
    mx = fmaxf(mx, __shfl_xor(mx, off));

  float sum = 0.0f;
  for (int j = lane; j < len; j += 64) sum += __expf(row[j] - mx);
#pragma unroll
  for (int off = 32; off > 0; off >>= 1) sum += __shfl_xor(sum, off);
  const float inv = 1.0f / sum;

  for (int j = lane; j < len; j += 64)
    arow[j] = f2bf(__expf(row[j] - mx) * inv);
  for (int j = len + lane; j < T_DIM; j += 64) arow[j] = 0;
}

// ---------------------------------------------------------------------------
__global__ __launch_bounds__(256) void attnv_mfma_kernel(
    const u16* __restrict__ attn, const u16* __restrict__ vT,
    u16* __restrict__ o1) {
  const int b = blockIdx.z;
  const int m0 = blockIdx.y * 128;
  const int n0 = blockIdx.x * 128;
  f4_t acc[4][4];
#pragma unroll
  for (int i = 0; i < 4; ++i)
#pragma unroll
    for (int j = 0; j < 4; ++j) acc[i][j] = (f4_t){0.f, 0.f, 0.f, 0.f};
  mfma_gemm_nt(attn + (size_t)b * T_DIM * T_DIM,
               vT + (size_t)b * D_DIM * T_DIM, T_DIM, T_DIM, m0, n0,
               m0 + 128, acc);
  EPI_PREAMBLE
  u16* out = o1 + (size_t)b * T_DIM * D_DIM;
#pragma unroll
  for (int i = 0; i < 4; ++i)
#pragma unroll
    for (int j = 0; j < 4; ++j) {
      const int cc = n0 + wcol + j * 16 + m16;
#pragma unroll
      for (int r = 0; r < 4; ++r) {
        const size_t rr = m0 + wrow + i * 16 + q * 4 + r;
        out[rr * D_DIM + cc] = f2bf(acc[i][j][r]);
      }
    }
}

// ---------------------------------------------------------------------------
__global__ __launch_bounds__(256) void out_mfma_kernel(
    const u16* __restrict__ o1, const u16* __restrict__ Wbf,
    float* __restrict__ out) {
  f4_t acc[4][4];
#pragma unroll
  for (int i = 0; i < 4; ++i)
#pragma unroll
    for (int j = 0; j < 4; ++j) acc[i][j] = (f4_t){0.f, 0.f, 0.f, 0.f};
  const int m0 = blockIdx.y * 128;
  const int n0 = blockIdx.x * 128;
  mfma_gemm_nt(o1, Wbf, D_DIM, D_DIM, m0, n0, D_DIM, acc);
  EPI_PREAMBLE
#pragma unroll
  for (int i = 0; i < 4; ++i)
#pragma unroll
    for (int j = 0; j < 4; ++j) {
      const int cc = n0 + wcol + j * 16 + m16;
#pragma unroll
      for (int r = 0; r < 4; ++r) {
        const size_t rr = m0 + wrow + i * 16 + q * 4 + r;
        out[rr * D_DIM + cc] = acc[i][j][r];
      }
    }
}

// ---------------------------------------------------------------------------
// Workspace (SZ = B*T*D = 8,388,608), total ~156 MiB (proven):
//   R0: 2*SZ fp32 (64 MiB) = scores; hosts xbf (bf16 x) early (dead by then)
//   uqb, vbf, vT, bq1(aq), bkf(ak): 5 x SZ u16 (80 MiB)
//   wqkvb 3M, woutb 1M, gqsw 1M, gksw 1M u16 (12 MiB)
// ukb (bf16 u_k) lives in d_out, fully overwritten by the final GEMM.
// attn (2*SZ u16) over [bq1|bkf] (dead after scores); o1 over uqb (dead).
// ---------------------------------------------------------------------------
extern "C" void kernel_launch(void* const* d_in, const int* in_sizes, int n_in,
                              void* d_out, int out_size, void* d_ws,
                              size_t ws_size, hipStream_t stream) {
  (void)in_sizes; (void)n_in; (void)out_size; (void)ws_size;
  const float* x = (const float*)d_in[0];
  const float* Wqkv = (const float*)d_in[1];
  const float* Wout = (const float*)d_in[2];
  const float* Gq_raw = (const float*)d_in[3];
  const float* llq = (const float*)d_in[4];
  const float* Gk_raw = (const float*)d_in[5];
  const float* llk = (const float*)d_in[6];
  float* out = (float*)d_out;

  const size_t SZ = (size_t)B_DIM * T_DIM * D_DIM;  // 8,388,608
  u16* base = (u16*)d_ws;
  float* sc = (float*)base;          // 2*SZ fp32 (= 4*SZ u16)
  u16* xbf = base;                   // bf16 x over R0 start (dead before sc)
  u16* uqb = base + 4 * SZ;
  u16* vbf = base + 5 * SZ;
  u16* vT  = base + 6 * SZ;
  u16* bq1 = base + 7 * SZ;          // final aq
  u16* bkf = base + 8 * SZ;          // final ak
  u16* wqkvb = base + 9 * SZ;                    // 3M
  u16* woutb = wqkvb + 3 * 1024 * 1024;          // 1M
  u16* gqsw = woutb + 1024 * 1024;               // 1M
  u16* gksw = gqsw + 1024 * 1024;                // 1M
  u16* ukb = (u16*)d_out;            // bf16 u_k in d_out until final GEMM
  u16* attn = bq1;                   // 2*SZ over bq1+bkf (dead after scores)
  u16* o1 = uqb;                     // dead after LCA

  const dim3 blk(256);

  cvt_bf16_kernel<<<dim3((int)(SZ / 4 / 256)), blk, 0, stream>>>(x, xbf,
                                                                 (int)(SZ / 4));
  cvt_bf16_kernel<<<dim3(3 * 1024), blk, 0, stream>>>(Wqkv, wqkvb,
                                                      3 * 1024 * 1024 / 4);
  cvt_bf16_kernel<<<dim3(1024), blk, 0, stream>>>(Wout, woutb,
                                                  1024 * 1024 / 4);
  prep_Gsw_kernel<<<dim3(512), blk, 0, stream>>>(Gq_raw, gqsw);
  prep_Gsw_kernel<<<dim3(512), blk, 0, stream>>>(Gk_raw, gksw);

  // qkv: 1536 blocks, supertile-swizzled; bf16 outputs
  qkv_mfma_kernel<<<dim3(1536), blk, 0, stream>>>(xbf, wqkvb, uqb, ukb, vbf);
  transpose_bf16_kernel<<<dim3(16, 32, 4), blk, 0, stream>>>(vbf, vT);

  // fused LCA (R7-proven): both chains, one dispatch, 512-thread blocks
  lca_fused_kernel<<<dim3(512), dim3(512), 0, stream>>>(uqb, ukb, gqsw, gksw,
                                                        llq, llk, bq1, bkf);

  scores_mfma_kernel<<<dim3(16, 16, 4), blk, 0, stream>>>(bq1, bkf, sc);
  softmax_attn_kernel<<<dim3(B_DIM * T_DIM / 4), blk, 0, stream>>>(sc, attn);
  attnv_mfma_kernel<<<dim3(8, 16, 4), blk, 0, stream>>>(attn, vT, o1);
  out_mfma_kernel<<<dim3(8, 64), blk, 0, stream>>>(o1, woutb, out);
}

// Round 10
// 1212.071 us; speedup vs baseline: 1.1620x; 1.0058x over previous
//
#include <hip/hip_runtime.h>
#include <math.h>

#define B_DIM 4
#define T_DIM 2048
#define D_DIM 1024
#define ETA 0.1f
#define N_ITERS 10

typedef unsigned short u16;
typedef __attribute__((ext_vector_type(8))) short bf8_t;   // 8 bf16 (4 VGPRs)
typedef __attribute__((ext_vector_type(4))) float f4_t;    // 4 fp32 acc
typedef __attribute__((ext_vector_type(16))) float f16v;   // 16 fp32 acc (32x32)

__device__ __forceinline__ u16 f2bf(float f) {
  union { float f; unsigned u; } x;
  x.f = f;
  unsigned r = x.u + 0x7FFFu + ((x.u >> 16) & 1u);  // RNE
  return (u16)(r >> 16);
}
__device__ __forceinline__ float bf2f(u16 h) {
  union { unsigned u; float f; } x;
  x.u = ((unsigned)h) << 16;
  return x.f;
}

__device__ __forceinline__ float soft_thresh(float v, float lam) {
  return copysignf(fmaxf(fabsf(v) - lam, 0.0f), v);
}

// ---------------------------------------------------------------------------
// bf16 MFMA NT GEMM core: C(128x128 at m0,n0) = A[M x K] * B^T (B is [N][K]).
// 256 threads = 4 waves (2x2), each wave 64x64 = 4x4 mfma 16x16x32 tiles.
// ---------------------------------------------------------------------------
__device__ __forceinline__ void mfma_gemm_nt(const u16* __restrict__ A,
                                             const u16* __restrict__ Bm,
                                             int lda, int ldb,
                                             int m0, int n0, int kEnd,
                                             f4_t acc[4][4]) {
  __shared__ short As[128][72];
  __shared__ short Bs[128][72];
  const int tid = threadIdx.x;
  const int lane = tid & 63;
  const int wave = tid >> 6;
  const int m16 = lane & 15;
  const int q = lane >> 4;
  const int wrow = (wave >> 1) * 64;
  const int wcol = (wave & 1) * 64;
  const int sr = tid >> 3;   // staging row base (0..31)
  const int sc8 = tid & 7;   // k-octet (8 bf16 = 16B)

  float4 apf[4], bpf[4];
#pragma unroll
  for (int p = 0; p < 4; ++p) {
    apf[p] = *(const float4*)(A + (size_t)(m0 + sr + p * 32) * lda + sc8 * 8);
    bpf[p] = *(const float4*)(Bm + (size_t)(n0 + sr + p * 32) * ldb + sc8 * 8);
  }

  for (int k0 = 0; k0 < kEnd; k0 += 64) {
    __syncthreads();
#pragma unroll
    for (int p = 0; p < 4; ++p) {
      *(float4*)&As[sr + p * 32][sc8 * 8] = apf[p];
      *(float4*)&Bs[sr + p * 32][sc8 * 8] = bpf[p];
    }
    __syncthreads();
    if (k0 + 64 < kEnd) {
      const int kn = k0 + 64 + sc8 * 8;
#pragma unroll
      for (int p = 0; p < 4; ++p) {
        apf[p] = *(const float4*)(A + (size_t)(m0 + sr + p * 32) * lda + kn);
        bpf[p] = *(const float4*)(Bm + (size_t)(n0 + sr + p * 32) * ldb + kn);
      }
    }
#pragma unroll
    for (int s = 0; s < 2; ++s) {
      bf8_t af[4], bb[4];
#pragma unroll
      for (int i = 0; i < 4; ++i)
        af[i] = *(const bf8_t*)&As[wrow + i * 16 + m16][s * 32 + q * 8];
#pragma unroll
      for (int j = 0; j < 4; ++j)
        bb[j] = *(const bf8_t*)&Bs[wcol + j * 16 + m16][s * 32 + q * 8];
#pragma unroll
      for (int i = 0; i < 4; ++i)
#pragma unroll
        for (int j = 0; j < 4; ++j)
          acc[i][j] = __builtin_amdgcn_mfma_f32_16x16x32_bf16(
              af[i], bb[j], acc[i][j], 0, 0, 0);
    }
  }
}

// C/D layout 16x16 (verified m89): col = lane&15, row = (lane>>4)*4 + reg.
#define EPI_PREAMBLE                                   \
  const int tid = threadIdx.x;                         \
  const int lane = tid & 63;                           \
  const int wave = tid >> 6;                           \
  const int m16 = lane & 15;                           \
  const int q = lane >> 4;                             \
  const int wrow = (wave >> 1) * 64;                   \
  const int wcol = (wave & 1) * 64;

// ---------------------------------------------------------------------------
// Merged fp32 -> bf16 conversion for x, Wqkv, Wout in one dispatch.
// ---------------------------------------------------------------------------
__global__ __launch_bounds__(256) void cvt_all_kernel(
    const float* __restrict__ x, u16* __restrict__ xb, int nx4,
    const float* __restrict__ w1, u16* __restrict__ w1b, int nw14,
    const float* __restrict__ w2, u16* __restrict__ w2b, int nw24) {
  int i = blockIdx.x * 256 + threadIdx.x;
  const float* src;
  u16* dst;
  if (i < nx4) {
    src = x; dst = xb;
  } else if (i < nx4 + nw14) {
    i -= nx4; src = w1; dst = w1b;
  } else {
    i -= nx4 + nw14;
    if (i >= nw24) return;
    src = w2; dst = w2b;
  }
  const float4 v = ((const float4*)src)[i];
  ushort4 o;
  o.x = f2bf(v.x); o.y = f2bf(v.y); o.z = f2bf(v.z); o.w = f2bf(v.w);
  ((ushort4*)dst)[i] = o;
}

// ---------------------------------------------------------------------------
// G -> fragment-sequential swizzled layout (coalesced version).
// Output semantics (consumer-verified): flat = ((T*64 + c)*64 + w)*8 + j
// holds G[n][k] with n = T*32 + (w&31), k = c*16 + (w>>5)*8 + j.
// Block (bx,by) handles k-tile K0=bx*64, n-tile N0=by*64: stage Graw tiles
// (N0,K0) and (K0,N0) coalesced into LDS, symmetrize from LDS, write Gsw
// with fully-coalesced float4 stores.
// ---------------------------------------------------------------------------
__global__ __launch_bounds__(256) void prep_Gsw_kernel(
    const float* __restrict__ Graw, u16* __restrict__ Gsw) {
  __shared__ float At[64][65];   // Graw[N0+i][K0+j]
  __shared__ float Bt[64][65];   // Graw[K0+i][N0+j]
  const int K0 = (blockIdx.x & 15) * 64;
  const int N0 = (blockIdx.x >> 4) * 64;
  const int tid = threadIdx.x;
  const int row = tid >> 2;          // 0..63
  const int c4b = tid & 3;           // float4 column group base
#pragma unroll
  for (int rep = 0; rep < 4; ++rep) {
    const int c4 = c4b + rep * 4;    // 0..15
    *(float4*)&At[row][c4 * 4] =
        *(const float4*)(Graw + (size_t)(N0 + row) * D_DIM + K0 + c4 * 4);
    *(float4*)&Bt[row][c4 * 4] =
        *(const float4*)(Graw + (size_t)(K0 + row) * D_DIM + N0 + c4 * 4);
  }
  __syncthreads();
#pragma unroll
  for (int rep = 0; rep < 2; ++rep) {
    const int task = tid + rep * 256;   // 0..511
    const int tc = task >> 6;           // 0..7
    const int w = task & 63;
    const int t_l = tc >> 2;            // 0..1
    const int c_l = tc & 3;             // 0..3
    const int i = t_l * 32 + (w & 31);          // n-local
    const int kb = c_l * 16 + (w >> 5) * 8;     // k-local base
    union { u16 s[8]; float4 v; } o;
#pragma unroll
    for (int j = 0; j < 8; ++j) {
      const int kl = kb + j;
      const float g = (N0 + i == K0 + kl)
          ? 0.0f
          : 0.5f * (At[i][kl] + Bt[kl][i]);
      o.s[j] = f2bf(g);
    }
    const size_t T = (size_t)(N0 >> 5) + t_l;
    const size_t c = (size_t)(K0 >> 4) + c_l;
    *(float4*)(Gsw + ((T * 64 + c) * 64 + w) * 8) = o.v;
  }
}

// ---------------------------------------------------------------------------
// qkv = x @ Wqkv^T -> all outputs bf16: uqb / ukb (in d_out) / vbf.
// 1-D grid of 1536 blocks, supertile-swizzled (R7-proven).
// ---------------------------------------------------------------------------
__global__ __launch_bounds__(256) void qkv_mfma_kernel(
    const u16* __restrict__ xbf, const u16* __restrict__ Wbf,
    u16* __restrict__ uqb, u16* __restrict__ ukb, u16* __restrict__ vbf) {
  const int bid = blockIdx.x;
  const int g = bid / 192;
  const int r = bid % 192;
  const int m0 = (g * 8 + (r & 7)) * 128;
  const int n0 = (r >> 3) * 128;
  f4_t acc[4][4];
#pragma unroll
  for (int i = 0; i < 4; ++i)
#pragma unroll
    for (int j = 0; j < 4; ++j) acc[i][j] = (f4_t){0.f, 0.f, 0.f, 0.f};
  mfma_gemm_nt(xbf, Wbf, D_DIM, D_DIM, m0, n0, D_DIM, acc);
  EPI_PREAMBLE
  const int which = n0 >> 10;
  u16* dst = (which == 0) ? uqb : ((which == 1) ? ukb : vbf);
  const int nloc0 = n0 & 1023;
#pragma unroll
  for (int i = 0; i < 4; ++i)
#pragma unroll
    for (int j = 0; j < 4; ++j) {
      const int cc = nloc0 + wcol + j * 16 + m16;
#pragma unroll
      for (int r2 = 0; r2 < 4; ++r2) {
        const size_t rr = m0 + wrow + i * 16 + q * 4 + r2;
        dst[rr * D_DIM + cc] = f2bf(acc[i][j][r2]);
      }
    }
}

// ---------------------------------------------------------------------------
__global__ __launch_bounds__(256) void transpose_bf16_kernel(
    const u16* __restrict__ src, u16* __restrict__ dst) {
  __shared__ short Ls[64][72];
  const int b = blockIdx.z;
  const int d0 = blockIdx.x * 64;
  const int t0 = blockIdx.y * 64;
  const int tid = threadIdx.x;
#pragma unroll
  for (int rep = 0; rep < 2; ++rep) {
    const int u = rep * 256 + tid;
    const int r = u >> 3;
    const int c8 = u & 7;
    const float4 v = *(const float4*)(src + (size_t)b * T_DIM * D_DIM +
                                      (size_t)(t0 + r) * D_DIM + d0 + c8 * 8);
    *(float4*)&Ls[r][c8 * 8] = v;
  }
  __syncthreads();
#pragma unroll
  for (int rep = 0; rep < 2; ++rep) {
    const int u = rep * 256 + tid;
    const int d = u >> 3;
    const int t8 = u & 7;
    union { u16 s[8]; float4 v; } tmp;
#pragma unroll
    for (int l = 0; l < 8; ++l) tmp.s[l] = (u16)Ls[t8 * 8 + l][d];
    *(float4*)(dst + (size_t)b * D_DIM * T_DIM + (size_t)(d0 + d) * T_DIM +
               t0 + t8 * 8) = tmp.v;
  }
}

// ---------------------------------------------------------------------------
// Fused LCA chain (R7-proven exact): all 10 iterations in one kernel,
// mfma_32x32x16, 2-slot G-fragment register prefetch. Register budget
// vreg 64 + bb 32 + misc fits the 128-arch-VGPR allocation: no spill
// (R8's 4-slot variant spilled -> reverted; structure is at its plateau).
// ---------------------------------------------------------------------------
__global__ __launch_bounds__(512) void lca_fused_kernel(
    const u16* __restrict__ uqb, const u16* __restrict__ ukb,
    const u16* __restrict__ Gqsw, const u16* __restrict__ Gksw,
    const float* __restrict__ llq, const float* __restrict__ llk,
    u16* __restrict__ aq_out, u16* __restrict__ ak_out) {
  __shared__ u16 a_lds[32][1032];
  const int b = blockIdx.x;
  const int chain = (b >> 2) & 1;                 // b%8: 0-3 q, 4-7 k (XCD map)
  const int mb = ((b >> 3) << 2) | (b & 3);       // 0..255
  const int m0 = mb * 32;
  const u16* __restrict__ ub = chain ? ukb : uqb;
  const u16* __restrict__ Gsw = chain ? Gksw : Gqsw;
  u16* __restrict__ aout = chain ? ak_out : aq_out;
  const float lam = expf(chain ? llk[0] : llq[0]);

  const int tid = threadIdx.x;
  const int lane = tid & 63;
  const int wave = tid >> 6;      // 0..7
  const int n32 = lane & 31;
  const int l5 = lane >> 5;       // 0/1
  const int col0 = wave * 128;

  float vreg[4][16];

  // ---- init (iter 0): v = ETA*u ; a0 = soft(v) into a_lds
#pragma unroll
  for (int nt = 0; nt < 4; ++nt) {
    const int col_g = col0 + nt * 32 + n32;
#pragma unroll
    for (int reg = 0; reg < 16; ++reg) {
      const int row = (reg & 3) + 8 * (reg >> 2) + 4 * l5;
      const float uu = bf2f(ub[(size_t)(m0 + row) * D_DIM + col_g]);
      const float v = ETA * uu;
      vreg[nt][reg] = v;
      a_lds[row][col_g] = f2bf(soft_thresh(v, lam));
    }
  }

  // per-tile fragment base: Gsw + t*64*512 + lane*8 (elems); step c = +512
  const u16* gb[4];
#pragma unroll
  for (int nt = 0; nt < 4; ++nt)
    gb[nt] = Gsw + ((size_t)(wave * 4 + nt) * 64) * 512 + lane * 8;

  for (int it = 1; it < N_ITERS; ++it) {
    __syncthreads();  // a_lds complete (init or previous epilogue)
    f16v acc[4];
#pragma unroll
    for (int nt = 0; nt < 4; ++nt)
#pragma unroll
      for (int r = 0; r < 16; ++r) acc[nt][r] = 0.0f;

    bf8_t bb0[4], bb1[4];
#pragma unroll
    for (int nt = 0; nt < 4; ++nt) bb0[nt] = *(const bf8_t*)(gb[nt]);

#pragma unroll 1
    for (int c = 0; c < 64; c += 2) {
#pragma unroll
      for (int nt = 0; nt < 4; ++nt)
        bb1[nt] = *(const bf8_t*)(gb[nt] + (size_t)(c + 1) * 512);
      {
        const bf8_t af = *(const bf8_t*)&a_lds[n32][c * 16 + l5 * 8];
#pragma unroll
        for (int nt = 0; nt < 4; ++nt)
          acc[nt] = __builtin_amdgcn_mfma_f32_32x32x16_bf16(af, bb0[nt],
                                                            acc[nt], 0, 0, 0);
      }
      if (c + 2 < 64) {
#pragma unroll
        for (int nt = 0; nt < 4; ++nt)
          bb0[nt] = *(const bf8_t*)(gb[nt] + (size_t)(c + 2) * 512);
      }
      {
        const bf8_t af = *(const bf8_t*)&a_lds[n32][(c + 1) * 16 + l5 * 8];
#pragma unroll
        for (int nt = 0; nt < 4; ++nt)
          acc[nt] = __builtin_amdgcn_mfma_f32_32x32x16_bf16(af, bb1[nt],
                                                            acc[nt], 0, 0, 0);
      }
    }
    __syncthreads();  // all waves done READING a_lds; safe to overwrite

    const bool last = (it == N_ITERS - 1);
#pragma unroll
    for (int nt = 0; nt < 4; ++nt) {
      const int col_g = col0 + nt * 32 + n32;
#pragma unroll
      for (int reg = 0; reg < 16; ++reg) {
        const int row = (reg & 3) + 8 * (reg >> 2) + 4 * l5;
        const float uu = bf2f(ub[(size_t)(m0 + row) * D_DIM + col_g]);
        float v = vreg[nt][reg];
        v += ETA * (uu - v - acc[nt][reg]);
        vreg[nt][reg] = v;
        const u16 av = f2bf(soft_thresh(v, lam));
        a_lds[row][col_g] = av;
        if (last) aout[(size_t)(m0 + row) * D_DIM + col_g] = av;
      }
    }
  }
}

// ---------------------------------------------------------------------------
__global__ __launch_bounds__(256) void scores_mfma_kernel(
    const u16* __restrict__ aq, const u16* __restrict__ ak,
    float* __restrict__ sc) {
  const int b = blockIdx.z;
  const int m0 = blockIdx.y * 128;
  const int n0 = blockIdx.x * 128;
  if (n0 > m0 + 127) return;  // uniform early exit, before any barrier
  f4_t acc[4][4];
#pragma unroll
  for (int i = 0; i < 4; ++i)
#pragma unroll
    for (int j = 0; j < 4; ++j) acc[i][j] = (f4_t){0.f, 0.f, 0.f, 0.f};
  mfma_gemm_nt(aq + (size_t)b * T_DIM * D_DIM,
               ak + (size_t)b * T_DIM * D_DIM, D_DIM, D_DIM, m0, n0, D_DIM,
               acc);
  EPI_PREAMBLE
  float* out = sc + (size_t)b * T_DIM * T_DIM;
  const float scale = 0.03125f;  // 1/sqrt(1024)
#pragma unroll
  for (int i = 0; i < 4; ++i)
#pragma unroll
    for (int j = 0; j < 4; ++j) {
      const int cc = n0 + wcol + j * 16 + m16;
#pragma unroll
      for (int r = 0; r < 4; ++r) {
        const size_t rr = m0 + wrow + i * 16 + q * 4 + r;
        out[rr * T_DIM + cc] = acc[i][j][r] * scale;
      }
    }
}

// ---------------------------------------------------------------------------
// Causal softmax, one WAVE per row (no LDS, no barriers): 4 rows / block.
// ---------------------------------------------------------------------------
__global__ __launch_bounds__(256) void softmax_attn_kernel(
    const float* __restrict__ sc, u16* __restrict__ attn) {
  const int r = blockIdx.x * 4 + (threadIdx.x >> 6);  // global row 0..8191
  const int lane = threadIdx.x & 63;
  const int b = r >> 11;
  const int i = r & (T_DIM - 1);
  const float* row = sc + ((size_t)b * T_DIM + i) * T_DIM;
  u16* arow = attn + ((size_t)b * T_DIM + i) * T_DIM;
  const int len = i + 1;

  float mx = -INFINITY;
  for (int j = lane; j < len; j += 64) mx = fmaxf(mx, row[j]);
#pragma unroll
  for (int off = 32; off > 0; off >>= 1)
    mx = fmaxf(mx, __shfl_xor(mx, off));

  float sum = 0.0f;
  for (int j = lane; j < len; j += 64) sum += __expf(row[j] - mx);
#pragma unroll
  for (int off = 32; off > 0; off >>= 1) sum += __shfl_xor(sum, off);
  const float inv = 1.0f / sum;

  for (int j = lane; j < len; j += 64)
    arow[j] = f2bf(__expf(row[j] - mx) * inv);
  for (int j = len + lane; j < T_DIM; j += 64) arow[j] = 0;
}

// ---------------------------------------------------------------------------
__global__ __launch_bounds__(256) void attnv_mfma_kernel(
    const u16* __restrict__ attn, const u16* __restrict__ vT,
    u16* __restrict__ o1) {
  const int b = blockIdx.z;
  const int m0 = blockIdx.y * 128;
  const int n0 = blockIdx.x * 128;
  f4_t acc[4][4];
#pragma unroll
  for (int i = 0; i < 4; ++i)
#pragma unroll
    for (int j = 0; j < 4; ++j) acc[i][j] = (f4_t){0.f, 0.f, 0.f, 0.f};
  mfma_gemm_nt(attn + (size_t)b * T_DIM * T_DIM,
               vT + (size_t)b * D_DIM * T_DIM, T_DIM, T_DIM, m0, n0,
               m0 + 128, acc);
  EPI_PREAMBLE
  u16* out = o1 + (size_t)b * T_DIM * D_DIM;
#pragma unroll
  for (int i = 0; i < 4; ++i)
#pragma unroll
    for (int j = 0; j < 4; ++j) {
      const int cc = n0 + wcol + j * 16 + m16;
#pragma unroll
      for (int r = 0; r < 4; ++r) {
        const size_t rr = m0 + wrow + i * 16 + q * 4 + r;
        out[rr * D_DIM + cc] = f2bf(acc[i][j][r]);
      }
    }
}

// ---------------------------------------------------------------------------
__global__ __launch_bounds__(256) void out_mfma_kernel(
    const u16* __restrict__ o1, const u16* __restrict__ Wbf,
    float* __restrict__ out) {
  f4_t acc[4][4];
#pragma unroll
  for (int i = 0; i < 4; ++i)
#pragma unroll
    for (int j = 0; j < 4; ++j) acc[i][j] = (f4_t){0.f, 0.f, 0.f, 0.f};
  const int m0 = blockIdx.y * 128;
  const int n0 = blockIdx.x * 128;
  mfma_gemm_nt(o1, Wbf, D_DIM, D_DIM, m0, n0, D_DIM, acc);
  EPI_PREAMBLE
#pragma unroll
  for (int i = 0; i < 4; ++i)
#pragma unroll
    for (int j = 0; j < 4; ++j) {
      const int cc = n0 + wcol + j * 16 + m16;
#pragma unroll
      for (int r = 0; r < 4; ++r) {
        const size_t rr = m0 + wrow + i * 16 + q * 4 + r;
        out[rr * D_DIM + cc] = acc[i][j][r];
      }
    }
}

// ---------------------------------------------------------------------------
// Workspace (SZ = B*T*D = 8,388,608), total ~156 MiB (proven):
//   R0: 2*SZ fp32 (64 MiB) = scores; hosts xbf (bf16 x) early (dead by then)
//   uqb, vbf, vT, bq1(aq), bkf(ak): 5 x SZ u16 (80 MiB)
//   wqkvb 3M, woutb 1M, gqsw 1M, gksw 1M u16 (12 MiB)
// ukb (bf16 u_k) lives in d_out, fully overwritten by the final GEMM.
// attn (2*SZ u16) over [bq1|bkf] (dead after scores); o1 over uqb (dead).
// ---------------------------------------------------------------------------
extern "C" void kernel_launch(void* const* d_in, const int* in_sizes, int n_in,
                              void* d_out, int out_size, void* d_ws,
                              size_t ws_size, hipStream_t stream) {
  (void)in_sizes; (void)n_in; (void)out_size; (void)ws_size;
  const float* x = (const float*)d_in[0];
  const float* Wqkv = (const float*)d_in[1];
  const float* Wout = (const float*)d_in[2];
  const float* Gq_raw = (const float*)d_in[3];
  const float* llq = (const float*)d_in[4];
  const float* Gk_raw = (const float*)d_in[5];
  const float* llk = (const float*)d_in[6];
  float* out = (float*)d_out;

  const size_t SZ = (size_t)B_DIM * T_DIM * D_DIM;  // 8,388,608
  u16* base = (u16*)d_ws;
  float* sc = (float*)base;          // 2*SZ fp32 (= 4*SZ u16)
  u16* xbf = base;                   // bf16 x over R0 start (dead before sc)
  u16* uqb = base + 4 * SZ;
  u16* vbf = base + 5 * SZ;
  u16* vT  = base + 6 * SZ;
  u16* bq1 = base + 7 * SZ;          // final aq
  u16* bkf = base + 8 * SZ;          // final ak
  u16* wqkvb = base + 9 * SZ;                    // 3M
  u16* woutb = wqkvb + 3 * 1024 * 1024;          // 1M
  u16* gqsw = woutb + 1024 * 1024;               // 1M
  u16* gksw = gqsw + 1024 * 1024;                // 1M
  u16* ukb = (u16*)d_out;            // bf16 u_k in d_out until final GEMM
  u16* attn = bq1;                   // 2*SZ over bq1+bkf (dead after scores)
  u16* o1 = uqb;                     // dead after LCA

  const dim3 blk(256);

  // merged fp32->bf16 conversions: x (2,097,152 f4) + Wqkv (786,432) +
  // Wout (262,144) = 3,145,728 tasks -> 12288 blocks
  cvt_all_kernel<<<dim3(12288), blk, 0, stream>>>(
      x, xbf, (int)(SZ / 4), Wqkv, wqkvb, 3 * 1024 * 1024 / 4, Wout, woutb,
      1024 * 1024 / 4);
  prep_Gsw_kernel<<<dim3(256), blk, 0, stream>>>(Gq_raw, gqsw);
  prep_Gsw_kernel<<<dim3(256), blk, 0, stream>>>(Gk_raw, gksw);

  // qkv: 1536 blocks, supertile-swizzled; bf16 outputs
  qkv_mfma_kernel<<<dim3(1536), blk, 0, stream>>>(xbf, wqkvb, uqb, ukb, vbf);
  transpose_bf16_kernel<<<dim3(16, 32, 4), blk, 0, stream>>>(vbf, vT);

  // fused LCA (R7-proven): both chains, one dispatch, 512-thread blocks
  lca_fused_kernel<<<dim3(512), dim3(512), 0, stream>>>(uqb, ukb, gqsw, gksw,
                                                        llq, llk, bq1, bkf);

  scores_mfma_kernel<<<dim3(16, 16, 4), blk, 0, stream>>>(bq1, bkf, sc);
  softmax_attn_kernel<<<dim3(B_DIM * T_DIM / 4), blk, 0, stream>>>(sc, attn);
  attnv_mfma_kernel<<<dim3(8, 16, 4), blk, 0, stream>>>(attn, vT, o1);
  out_mfma_kernel<<<dim3(8, 64), blk, 0, stream>>>(o1, woutb, out);
}

// Round 11
// 1194.636 us; speedup vs baseline: 1.1789x; 1.0146x over previous
//
#include <hip/hip_runtime.h>
#include <math.h>

#define B_DIM 4
#define T_DIM 2048
#define D_DIM 1024
#define ETA 0.1f
#define N_ITERS 10

typedef unsigned short u16;
typedef __attribute__((ext_vector_type(8))) short bf8_t;   // 8 bf16 (4 VGPRs)
typedef __attribute__((ext_vector_type(4))) float f4_t;    // 4 fp32 acc
typedef __attribute__((ext_vector_type(16))) float f16v;   // 16 fp32 acc (32x32)

__device__ __forceinline__ u16 f2bf(float f) {
  union { float f; unsigned u; } x;
  x.f = f;
  unsigned r = x.u + 0x7FFFu + ((x.u >> 16) & 1u);  // RNE
  return (u16)(r >> 16);
}
__device__ __forceinline__ float bf2f(u16 h) {
  union { unsigned u; float f; } x;
  x.u = ((unsigned)h) << 16;
  return x.f;
}

__device__ __forceinline__ float soft_thresh(float v, float lam) {
  return copysignf(fmaxf(fabsf(v) - lam, 0.0f), v);
}

// ---------------------------------------------------------------------------
// bf16 MFMA NT GEMM core: C(128x128 at m0,n0) = A[M x K] * B^T (B is [N][K]).
// 256 threads = 4 waves (2x2), each wave 64x64 = 4x4 mfma 16x16x32 tiles.
// ---------------------------------------------------------------------------
__device__ __forceinline__ void mfma_gemm_nt(const u16* __restrict__ A,
                                             const u16* __restrict__ Bm,
                                             int lda, int ldb,
                                             int m0, int n0, int kEnd,
                                             f4_t acc[4][4]) {
  __shared__ short As[128][72];
  __shared__ short Bs[128][72];
  const int tid = threadIdx.x;
  const int lane = tid & 63;
  const int wave = tid >> 6;
  const int m16 = lane & 15;
  const int q = lane >> 4;
  const int wrow = (wave >> 1) * 64;
  const int wcol = (wave & 1) * 64;
  const int sr = tid >> 3;   // staging row base (0..31)
  const int sc8 = tid & 7;   // k-octet (8 bf16 = 16B)

  float4 apf[4], bpf[4];
#pragma unroll
  for (int p = 0; p < 4; ++p) {
    apf[p] = *(const float4*)(A + (size_t)(m0 + sr + p * 32) * lda + sc8 * 8);
    bpf[p] = *(const float4*)(Bm + (size_t)(n0 + sr + p * 32) * ldb + sc8 * 8);
  }

  for (int k0 = 0; k0 < kEnd; k0 += 64) {
    __syncthreads();
#pragma unroll
    for (int p = 0; p < 4; ++p) {
      *(float4*)&As[sr + p * 32][sc8 * 8] = apf[p];
      *(float4*)&Bs[sr + p * 32][sc8 * 8] = bpf[p];
    }
    __syncthreads();
    if (k0 + 64 < kEnd) {
      const int kn = k0 + 64 + sc8 * 8;
#pragma unroll
      for (int p = 0; p < 4; ++p) {
        apf[p] = *(const float4*)(A + (size_t)(m0 + sr + p * 32) * lda + kn);
        bpf[p] = *(const float4*)(Bm + (size_t)(n0 + sr + p * 32) * ldb + kn);
      }
    }
#pragma unroll
    for (int s = 0; s < 2; ++s) {
      bf8_t af[4], bb[4];
#pragma unroll
      for (int i = 0; i < 4; ++i)
        af[i] = *(const bf8_t*)&As[wrow + i * 16 + m16][s * 32 + q * 8];
#pragma unroll
      for (int j = 0; j < 4; ++j)
        bb[j] = *(const bf8_t*)&Bs[wcol + j * 16 + m16][s * 32 + q * 8];
#pragma unroll
      for (int i = 0; i < 4; ++i)
#pragma unroll
        for (int j = 0; j < 4; ++j)
          acc[i][j] = __builtin_amdgcn_mfma_f32_16x16x32_bf16(
              af[i], bb[j], acc[i][j], 0, 0, 0);
    }
  }
}

// C/D layout 16x16 (verified m89): col = lane&15, row = (lane>>4)*4 + reg.
#define EPI_PREAMBLE                                   \
  const int tid = threadIdx.x;                         \
  const int lane = tid & 63;                           \
  const int wave = tid >> 6;                           \
  const int m16 = lane & 15;                           \
  const int q = lane >> 4;                             \
  const int wrow = (wave >> 1) * 64;                   \
  const int wcol = (wave & 1) * 64;

// ---------------------------------------------------------------------------
// Merged fp32 -> bf16 conversion for x, Wqkv, Wout in one dispatch.
// ---------------------------------------------------------------------------
__global__ __launch_bounds__(256) void cvt_all_kernel(
    const float* __restrict__ x, u16* __restrict__ xb, int nx4,
    const float* __restrict__ w1, u16* __restrict__ w1b, int nw14,
    const float* __restrict__ w2, u16* __restrict__ w2b, int nw24) {
  int i = blockIdx.x * 256 + threadIdx.x;
  const float* src;
  u16* dst;
  if (i < nx4) {
    src = x; dst = xb;
  } else if (i < nx4 + nw14) {
    i -= nx4; src = w1; dst = w1b;
  } else {
    i -= nx4 + nw14;
    if (i >= nw24) return;
    src = w2; dst = w2b;
  }
  const float4 v = ((const float4*)src)[i];
  ushort4 o;
  o.x = f2bf(v.x); o.y = f2bf(v.y); o.z = f2bf(v.z); o.w = f2bf(v.w);
  ((ushort4*)dst)[i] = o;
}

// ---------------------------------------------------------------------------
// G -> fragment-sequential swizzled layout, PRE-SCALED by -ETA:
// Gsw holds -eta * (0.5*(Graw+Graw^T)), zero diag. With the accumulator
// entering the K-loop as (1-eta)*v + eta*u, the MFMA chain then directly
// produces v' = (1-eta)v + eta*u - eta*(a@G) -- v lives in acc registers.
// flat = ((T*64 + c)*64 + w)*8 + j holds G[n][k], n = T*32 + (w&31),
// k = c*16 + (w>>5)*8 + j.
// ---------------------------------------------------------------------------
__global__ __launch_bounds__(256) void prep_Gsw_kernel(
    const float* __restrict__ Graw, u16* __restrict__ Gsw) {
  __shared__ float At[64][65];   // Graw[N0+i][K0+j]
  __shared__ float Bt[64][65];   // Graw[K0+i][N0+j]
  const int K0 = (blockIdx.x & 15) * 64;
  const int N0 = (blockIdx.x >> 4) * 64;
  const int tid = threadIdx.x;
  const int row = tid >> 2;          // 0..63
  const int c4b = tid & 3;           // float4 column group base
#pragma unroll
  for (int rep = 0; rep < 4; ++rep) {
    const int c4 = c4b + rep * 4;    // 0..15
    *(float4*)&At[row][c4 * 4] =
        *(const float4*)(Graw + (size_t)(N0 + row) * D_DIM + K0 + c4 * 4);
    *(float4*)&Bt[row][c4 * 4] =
        *(const float4*)(Graw + (size_t)(K0 + row) * D_DIM + N0 + c4 * 4);
  }
  __syncthreads();
  const float s = -ETA * 0.5f;
#pragma unroll
  for (int rep = 0; rep < 2; ++rep) {
    const int task = tid + rep * 256;   // 0..511
    const int tc = task >> 6;           // 0..7
    const int w = task & 63;
    const int t_l = tc >> 2;            // 0..1
    const int c_l = tc & 3;             // 0..3
    const int i = t_l * 32 + (w & 31);          // n-local
    const int kb = c_l * 16 + (w >> 5) * 8;     // k-local base
    union { u16 sdat[8]; float4 v; } o;
#pragma unroll
    for (int j = 0; j < 8; ++j) {
      const int kl = kb + j;
      const float g = (N0 + i == K0 + kl)
          ? 0.0f
          : s * (At[i][kl] + Bt[kl][i]);
      o.sdat[j] = f2bf(g);
    }
    const size_t T = (size_t)(N0 >> 5) + t_l;
    const size_t c = (size_t)(K0 >> 4) + c_l;
    *(float4*)(Gsw + ((T * 64 + c) * 64 + w) * 8) = o.v;
  }
}

// ---------------------------------------------------------------------------
// qkv = x @ Wqkv^T -> all outputs bf16: uqb / ukb (in d_out) / vbf.
// 1-D grid of 1536 blocks, supertile-swizzled (R7-proven).
// ---------------------------------------------------------------------------
__global__ __launch_bounds__(256) void qkv_mfma_kernel(
    const u16* __restrict__ xbf, const u16* __restrict__ Wbf,
    u16* __restrict__ uqb, u16* __restrict__ ukb, u16* __restrict__ vbf) {
  const int bid = blockIdx.x;
  const int g = bid / 192;
  const int r = bid % 192;
  const int m0 = (g * 8 + (r & 7)) * 128;
  const int n0 = (r >> 3) * 128;
  f4_t acc[4][4];
#pragma unroll
  for (int i = 0; i < 4; ++i)
#pragma unroll
    for (int j = 0; j < 4; ++j) acc[i][j] = (f4_t){0.f, 0.f, 0.f, 0.f};
  mfma_gemm_nt(xbf, Wbf, D_DIM, D_DIM, m0, n0, D_DIM, acc);
  EPI_PREAMBLE
  const int which = n0 >> 10;
  u16* dst = (which == 0) ? uqb : ((which == 1) ? ukb : vbf);
  const int nloc0 = n0 & 1023;
#pragma unroll
  for (int i = 0; i < 4; ++i)
#pragma unroll
    for (int j = 0; j < 4; ++j) {
      const int cc = nloc0 + wcol + j * 16 + m16;
#pragma unroll
      for (int r2 = 0; r2 < 4; ++r2) {
        const size_t rr = m0 + wrow + i * 16 + q * 4 + r2;
        dst[rr * D_DIM + cc] = f2bf(acc[i][j][r2]);
      }
    }
}

// ---------------------------------------------------------------------------
__global__ __launch_bounds__(256) void transpose_bf16_kernel(
    const u16* __restrict__ src, u16* __restrict__ dst) {
  __shared__ short Ls[64][72];
  const int b = blockIdx.z;
  const int d0 = blockIdx.x * 64;
  const int t0 = blockIdx.y * 64;
  const int tid = threadIdx.x;
#pragma unroll
  for (int rep = 0; rep < 2; ++rep) {
    const int u = rep * 256 + tid;
    const int r = u >> 3;
    const int c8 = u & 7;
    const float4 v = *(const float4*)(src + (size_t)b * T_DIM * D_DIM +
                                      (size_t)(t0 + r) * D_DIM + d0 + c8 * 8);
    *(float4*)&Ls[r][c8 * 8] = v;
  }
  __syncthreads();
#pragma unroll
  for (int rep = 0; rep < 2; ++rep) {
    const int u = rep * 256 + tid;
    const int d = u >> 3;
    const int t8 = u & 7;
    union { u16 s[8]; float4 v; } tmp;
#pragma unroll
    for (int l = 0; l < 8; ++l) tmp.s[l] = (u16)Ls[t8 * 8 + l][d];
    *(float4*)(dst + (size_t)b * D_DIM * T_DIM + (size_t)(d0 + d) * T_DIM +
               t0 + t8 * 8) = tmp.v;
  }
}

// ---------------------------------------------------------------------------
// Fused LCA chain v6: v LIVES IN THE MFMA ACCUMULATOR.
// Gsw is pre-scaled by -eta, so with acc entering the K-loop as
// (1-eta)*v_t + eta*u, the MFMA chain produces v_{t+1} directly.
// The 64-VGPR vreg array of R7 is eliminated: total regs ~acc64+bb32+misc
// -> 3-4 waves/SIMD (up from 2), better G-load latency hiding.
// Epilogue: a=soft(acc) -> LDS; then acc = (1-eta)*acc + eta*u (u re-read
// bf16, L2-hot) overlapping the barrier wait. K-loop identical to R7.
// ---------------------------------------------------------------------------
__global__ __launch_bounds__(512) void lca_fused_kernel(
    const u16* __restrict__ uqb, const u16* __restrict__ ukb,
    const u16* __restrict__ Gqsw, const u16* __restrict__ Gksw,
    const float* __restrict__ llq, const float* __restrict__ llk,
    u16* __restrict__ aq_out, u16* __restrict__ ak_out) {
  __shared__ u16 a_lds[32][1032];
  const int b = blockIdx.x;
  const int chain = (b >> 2) & 1;                 // b%8: 0-3 q, 4-7 k (XCD map)
  const int mb = ((b >> 3) << 2) | (b & 3);       // 0..255
  const int m0 = mb * 32;
  const u16* __restrict__ ub = chain ? ukb : uqb;
  const u16* __restrict__ Gsw = chain ? Gksw : Gqsw;
  u16* __restrict__ aout = chain ? ak_out : aq_out;
  const float lam = expf(chain ? llk[0] : llq[0]);

  const int tid = threadIdx.x;
  const int lane = tid & 63;
  const int wave = tid >> 6;      // 0..7
  const int n32 = lane & 31;
  const int l5 = lane >> 5;       // 0/1
  const int col0 = wave * 128;

  f16v acc[4];                    // acc[nt] = v for this wave's 4 n-tiles

  // ---- init (iter 0): v1 = ETA*u ; a1 = soft(v1) -> LDS ;
  //      then pre-scale for iter 1: acc = (1-ETA)*v1 + ETA*u  (reuse uu)
#pragma unroll
  for (int nt = 0; nt < 4; ++nt) {
    const int col_g = col0 + nt * 32 + n32;
#pragma unroll
    for (int reg = 0; reg < 16; ++reg) {
      const int row = (reg & 3) + 8 * (reg >> 2) + 4 * l5;
      const float uu = bf2f(ub[(size_t)(m0 + row) * D_DIM + col_g]);
      const float v1 = ETA * uu;
      a_lds[row][col_g] = f2bf(soft_thresh(v1, lam));
      acc[nt][reg] = (1.0f - ETA) * v1 + ETA * uu;
    }
  }

  // per-tile fragment base: Gsw + t*64*512 + lane*8 (elems); step c = +512
  const u16* gb[4];
#pragma unroll
  for (int nt = 0; nt < 4; ++nt)
    gb[nt] = Gsw + ((size_t)(wave * 4 + nt) * 64) * 512 + lane * 8;

  for (int it = 1; it < N_ITERS; ++it) {
    __syncthreads();  // a_lds complete (init or previous epilogue)

    bf8_t bb0[4], bb1[4];
#pragma unroll
    for (int nt = 0; nt < 4; ++nt) bb0[nt] = *(const bf8_t*)(gb[nt]);

#pragma unroll 1
    for (int c = 0; c < 64; c += 2) {
#pragma unroll
      for (int nt = 0; nt < 4; ++nt)
        bb1[nt] = *(const bf8_t*)(gb[nt] + (size_t)(c + 1) * 512);
      {
        const bf8_t af = *(const bf8_t*)&a_lds[n32][c * 16 + l5 * 8];
#pragma unroll
        for (int nt = 0; nt < 4; ++nt)
          acc[nt] = __builtin_amdgcn_mfma_f32_32x32x16_bf16(af, bb0[nt],
                                                            acc[nt], 0, 0, 0);
      }
      if (c + 2 < 64) {
#pragma unroll
        for (int nt = 0; nt < 4; ++nt)
          bb0[nt] = *(const bf8_t*)(gb[nt] + (size_t)(c + 2) * 512);
      }
      {
        const bf8_t af = *(const bf8_t*)&a_lds[n32][(c + 1) * 16 + l5 * 8];
#pragma unroll
        for (int nt = 0; nt < 4; ++nt)
          acc[nt] = __builtin_amdgcn_mfma_f32_32x32x16_bf16(af, bb1[nt],
                                                            acc[nt], 0, 0, 0);
      }
    }
    __syncthreads();  // all waves done READING a_lds; safe to overwrite

    // acc now holds v_{t+1}. Epilogue: a -> LDS (+global on last);
    // then pre-scale acc for the next iteration.
    const bool last = (it == N_ITERS - 1);
#pragma unroll
    for (int nt = 0; nt < 4; ++nt) {
      const int col_g = col0 + nt * 32 + n32;
#pragma unroll
      for (int reg = 0; reg < 16; ++reg) {
        const int row = (reg & 3) + 8 * (reg >> 2) + 4 * l5;
        const u16 av = f2bf(soft_thresh(acc[nt][reg], lam));
        a_lds[row][col_g] = av;
        if (last) {
          aout[(size_t)(m0 + row) * D_DIM + col_g] = av;
        } else {
          const float uu = bf2f(ub[(size_t)(m0 + row) * D_DIM + col_g]);
          acc[nt][reg] = (1.0f - ETA) * acc[nt][reg] + ETA * uu;
        }
      }
    }
  }
}

// ---------------------------------------------------------------------------
__global__ __launch_bounds__(256) void scores_mfma_kernel(
    const u16* __restrict__ aq, const u16* __restrict__ ak,
    float* __restrict__ sc) {
  const int b = blockIdx.z;
  const int m0 = blockIdx.y * 128;
  const int n0 = blockIdx.x * 128;
  if (n0 > m0 + 127) return;  // uniform early exit, before any barrier
  f4_t acc[4][4];
#pragma unroll
  for (int i = 0; i < 4; ++i)
#pragma unroll
    for (int j = 0; j < 4; ++j) acc[i][j] = (f4_t){0.f, 0.f, 0.f, 0.f};
  mfma_gemm_nt(aq + (size_t)b * T_DIM * D_DIM,
               ak + (size_t)b * T_DIM * D_DIM, D_DIM, D_DIM, m0, n0, D_DIM,
               acc);
  EPI_PREAMBLE
  float* out = sc + (size_t)b * T_DIM * T_DIM;
  const float scale = 0.03125f;  // 1/sqrt(1024)
#pragma unroll
  for (int i = 0; i < 4; ++i)
#pragma unroll
    for (int j = 0; j < 4; ++j) {
      const int cc = n0 + wcol + j * 16 + m16;
#pragma unroll
      for (int r = 0; r < 4; ++r) {
        const size_t rr = m0 + wrow + i * 16 + q * 4 + r;
        out[rr * T_DIM + cc] = acc[i][j][r] * scale;
      }
    }
}

// ---------------------------------------------------------------------------
// Causal softmax, one WAVE per row (no LDS, no barriers): 4 rows / block.
// ---------------------------------------------------------------------------
__global__ __launch_bounds__(256) void softmax_attn_kernel(
    const float* __restrict__ sc, u16* __restrict__ attn) {
  const int r = blockIdx.x * 4 + (threadIdx.x >> 6);  // global row 0..8191
  const int lane = threadIdx.x & 63;
  const int b = r >> 11;
  const int i = r & (T_DIM - 1);
  const float* row = sc + ((size_t)b * T_DIM + i) * T_DIM;
  u16* arow = attn + ((size_t)b * T_DIM + i) * T_DIM;
  const int len = i + 1;

  float mx = -INFINITY;
  for (int j = lane; j < len; j += 64) mx = fmaxf(mx, row[j]);
#pragma unroll
  for (int off = 32; off > 0; off >>= 1)
    mx = fmaxf(mx, __shfl_xor(mx, off));

  float sum = 0.0f;
  for (int j = lane; j < len; j += 64) sum += __expf(row[j] - mx);
#pragma unroll
  for (int off = 32; off > 0; off >>= 1) sum += __shfl_xor(sum, off);
  const float inv = 1.0f / sum;

  for (int j = lane; j < len; j += 64)
    arow[j] = f2bf(__expf(row[j] - mx) * inv);
  for (int j = len + lane; j < T_DIM; j += 64) arow[j] = 0;
}

// ---------------------------------------------------------------------------
__global__ __launch_bounds__(256) void attnv_mfma_kernel(
    const u16* __restrict__ attn, const u16* __restrict__ vT,
    u16* __restrict__ o1) {
  const int b = blockIdx.z;
  const int m0 = blockIdx.y * 128;
  const int n0 = blockIdx.x * 128;
  f4_t acc[4][4];
#pragma unroll
  for (int i = 0; i < 4; ++i)
#pragma unroll
    for (int j = 0; j < 4; ++j) acc[i][j] = (f4_t){0.f, 0.f, 0.f, 0.f};
  mfma_gemm_nt(attn + (size_t)b * T_DIM * T_DIM,
               vT + (size_t)b * D_DIM * T_DIM, T_DIM, T_DIM, m0, n0,
               m0 + 128, acc);
  EPI_PREAMBLE
  u16* out = o1 + (size_t)b * T_DIM * D_DIM;
#pragma unroll
  for (int i = 0; i < 4; ++i)
#pragma unroll
    for (int j = 0; j < 4; ++j) {
      const int cc = n0 + wcol + j * 16 + m16;
#pragma unroll
      for (int r = 0; r < 4; ++r) {
        const size_t rr = m0 + wrow + i * 16 + q * 4 + r;
        out[rr * D_DIM + cc] = f2bf(acc[i][j][r]);
      }
    }
}

// ---------------------------------------------------------------------------
__global__ __launch_bounds__(256) void out_mfma_kernel(
    const u16* __restrict__ o1, const u16* __restrict__ Wbf,
    float* __restrict__ out) {
  f4_t acc[4][4];
#pragma unroll
  for (int i = 0; i < 4; ++i)
#pragma unroll
    for (int j = 0; j < 4; ++j) acc[i][j] = (f4_t){0.f, 0.f, 0.f, 0.f};
  const int m0 = blockIdx.y * 128;
  const int n0 = blockIdx.x * 128;
  mfma_gemm_nt(o1, Wbf, D_DIM, D_DIM, m0, n0, D_DIM, acc);
  EPI_PREAMBLE
#pragma unroll
  for (int i = 0; i < 4; ++i)
#pragma unroll
    for (int j = 0; j < 4; ++j) {
      const int cc = n0 + wcol + j * 16 + m16;
#pragma unroll
      for (int r = 0; r < 4; ++r) {
        const size_t rr = m0 + wrow + i * 16 + q * 4 + r;
        out[rr * D_DIM + cc] = acc[i][j][r];
      }
    }
}

// ---------------------------------------------------------------------------
// Workspace (SZ = B*T*D = 8,388,608), total ~156 MiB (proven):
//   R0: 2*SZ fp32 (64 MiB) = scores; hosts xbf (bf16 x) early (dead by then)
//   uqb, vbf, vT, bq1(aq), bkf(ak): 5 x SZ u16 (80 MiB)
//   wqkvb 3M, woutb 1M, gqsw 1M, gksw 1M u16 (12 MiB)
// ukb (bf16 u_k) lives in d_out, fully overwritten by the final GEMM.
// attn (2*SZ u16) over [bq1|bkf] (dead after scores); o1 over uqb (dead).
// ---------------------------------------------------------------------------
extern "C" void kernel_launch(void* const* d_in, const int* in_sizes, int n_in,
                              void* d_out, int out_size, void* d_ws,
                              size_t ws_size, hipStream_t stream) {
  (void)in_sizes; (void)n_in; (void)out_size; (void)ws_size;
  const float* x = (const float*)d_in[0];
  const float* Wqkv = (const float*)d_in[1];
  const float* Wout = (const float*)d_in[2];
  const float* Gq_raw = (const float*)d_in[3];
  const float* llq = (const float*)d_in[4];
  const float* Gk_raw = (const float*)d_in[5];
  const float* llk = (const float*)d_in[6];
  float* out = (float*)d_out;

  const size_t SZ = (size_t)B_DIM * T_DIM * D_DIM;  // 8,388,608
  u16* base = (u16*)d_ws;
  float* sc = (float*)base;          // 2*SZ fp32 (= 4*SZ u16)
  u16* xbf = base;                   // bf16 x over R0 start (dead before sc)
  u16* uqb = base + 4 * SZ;
  u16* vbf = base + 5 * SZ;
  u16* vT  = base + 6 * SZ;
  u16* bq1 = base + 7 * SZ;          // final aq
  u16* bkf = base + 8 * SZ;          // final ak
  u16* wqkvb = base + 9 * SZ;                    // 3M
  u16* woutb = wqkvb + 3 * 1024 * 1024;          // 1M
  u16* gqsw = woutb + 1024 * 1024;               // 1M
  u16* gksw = gqsw + 1024 * 1024;                // 1M
  u16* ukb = (u16*)d_out;            // bf16 u_k in d_out until final GEMM
  u16* attn = bq1;                   // 2*SZ over bq1+bkf (dead after scores)
  u16* o1 = uqb;                     // dead after LCA

  const dim3 blk(256);

  // merged fp32->bf16 conversions
  cvt_all_kernel<<<dim3(12288), blk, 0, stream>>>(
      x, xbf, (int)(SZ / 4), Wqkv, wqkvb, 3 * 1024 * 1024 / 4, Wout, woutb,
      1024 * 1024 / 4);
  prep_Gsw_kernel<<<dim3(256), blk, 0, stream>>>(Gq_raw, gqsw);
  prep_Gsw_kernel<<<dim3(256), blk, 0, stream>>>(Gk_raw, gksw);

  // qkv: 1536 blocks, supertile-swizzled; bf16 outputs
  qkv_mfma_kernel<<<dim3(1536), blk, 0, stream>>>(xbf, wqkvb, uqb, ukb, vbf);
  transpose_bf16_kernel<<<dim3(16, 32, 4), blk, 0, stream>>>(vbf, vT);

  // fused LCA v6 (v-in-accumulator): both chains, one dispatch
  lca_fused_kernel<<<dim3(512), dim3(512), 0, stream>>>(uqb, ukb, gqsw, gksw,
                                                        llq, llk, bq1, bkf);

  scores_mfma_kernel<<<dim3(16, 16, 4), blk, 0, stream>>>(bq1, bkf, sc);
  softmax_attn_kernel<<<dim3(B_DIM * T_DIM / 4), blk, 0, stream>>>(sc, attn);
  attnv_mfma_kernel<<<dim3(8, 16, 4), blk, 0, stream>>>(attn, vT, o1);
  out_mfma_kernel<<<dim3(8, 64), blk, 0, stream>>>(o1, woutb, out);
}